// Round 6
// baseline (1704.896 us; speedup 1.0000x reference)
//
#include <hip/hip_runtime.h>
#include <cstdint>
#include <cstddef>

// ---------------- problem constants ----------------
#define B_   16
#define L_   1022
#define E_   1280
#define D_   512
#define H_   8
#define FF_  2048
#define NL_  4
#define DH_  64
#define BL_  (B_*L_)      // 16352
#define EPS_ 1e-5f

typedef unsigned short u16;
typedef unsigned int   u32;
typedef float f32x4 __attribute__((ext_vector_type(4)));
typedef short s16x8 __attribute__((ext_vector_type(8)));

__device__ __forceinline__ u16 f2bf(float f) {
    u32 u = __builtin_bit_cast(u32, f);
    u += 0x7fffu + ((u >> 16) & 1u);
    return (u16)(u >> 16);
}
__device__ __forceinline__ float bf2f(u16 u) {
    return __builtin_bit_cast(float, (u32)u << 16);
}

// async global->LDS, 16B/lane. Direct addrspace casts (NO uintptr_t detour:
// that reinterprets the flat-aperture bit pattern instead of converting).
__device__ __forceinline__ void gload_lds16(const u16* g, u16* l) {
    __builtin_amdgcn_global_load_lds(
        (const __attribute__((address_space(1))) void*)g,
        (__attribute__((address_space(3))) void*)l,
        16, 0, 0);
}

// ======================================================================
// fp32 -> bf16 cast, 8 elems/thread
// ======================================================================
__global__ __launch_bounds__(256)
void cast_k(const float* __restrict__ src, u16* __restrict__ dst, int n8) {
    int t = blockIdx.x * 256 + threadIdx.x;
    if (t >= n8) return;
    const float* s = src + (size_t)t * 8;
    float4 a = *(const float4*)(s);
    float4 b = *(const float4*)(s + 4);
    s16x8 o;
    o[0] = (short)f2bf(a.x); o[1] = (short)f2bf(a.y);
    o[2] = (short)f2bf(a.z); o[3] = (short)f2bf(a.w);
    o[4] = (short)f2bf(b.x); o[5] = (short)f2bf(b.y);
    o[6] = (short)f2bf(b.z); o[7] = (short)f2bf(b.w);
    *(s16x8*)(dst + (size_t)t * 8) = o;
}

// h1_w left half [128, 0:512] (row stride 1024) -> packed bf16 [128,512]
__global__ __launch_bounds__(256)
void h1cast_k(const float* __restrict__ src, u16* __restrict__ dst) {
    int t = blockIdx.x * 256 + threadIdx.x;
    if (t >= 128 * 512 / 8) return;
    int row = t >> 6, c8 = (t & 63) << 3;
    const float* s = src + (size_t)row * 1024 + c8;
    float4 a = *(const float4*)(s);
    float4 b = *(const float4*)(s + 4);
    s16x8 o;
    o[0] = (short)f2bf(a.x); o[1] = (short)f2bf(a.y);
    o[2] = (short)f2bf(a.z); o[3] = (short)f2bf(a.w);
    o[4] = (short)f2bf(b.x); o[5] = (short)f2bf(b.y);
    o[6] = (short)f2bf(b.z); o[7] = (short)f2bf(b.w);
    *(s16x8*)(dst + (size_t)row * 512 + c8) = o;
}

// ======================================================================
// RoPE cos/sin tables
// ======================================================================
__global__ void tables_k(float* __restrict__ ct, float* __restrict__ st) {
    int idx = blockIdx.x * blockDim.x + threadIdx.x;
    if (idx >= L_ * DH_) return;
    int l = idx / DH_;
    int d = idx % DH_;
    int j = d & 31;
    float invf = powf(10000.0f, -(float)(2 * j) / (float)DH_);
    float ang = (float)l * invf;
    ct[idx] = cosf(ang);
    st[idx] = sinf(ang);
}

// ======================================================================
// bf16 MFMA GEMM, m97 structure: C = act(A[M,K] @ W[N,K]^T + bias)(+resid)
// 128x128 tile, BK=64, 256 threads (4 waves 2x2), 4x4 16x16 frags/wave.
// global_load_lds width-16 staging into LINEAR LDS (required: lds dest is
// wave-uniform base + lane*16). 2 barriers per K-step.
// ======================================================================
template<bool RELU, bool RESID, bool OUTBF, bool ROWBIAS>
__global__ __launch_bounds__(256)
void mgemm_k(const u16* __restrict__ A, const u16* __restrict__ W,
             const float* __restrict__ bias, const float* __restrict__ resid,
             void* __restrict__ Cout, int M, int N, int K)
{
    __shared__ u16 As[128 * 64];
    __shared__ u16 Ws[128 * 64];
    const int nt = N >> 7;
    const int bx = blockIdx.x % nt;
    const int by = blockIdx.x / nt;
    const int m0 = by << 7, n0 = bx << 7;
    const int tid = threadIdx.x;
    const int lane = tid & 63, wid = tid >> 6;
    const int wr = wid >> 1, wc = wid & 1;
    const int lr = lane & 15, lk = lane >> 4;

    f32x4 acc[4][4];
#pragma unroll
    for (int m = 0; m < 4; m++)
#pragma unroll
        for (int n = 0; n < 4; n++) acc[m][n] = (f32x4)0.0f;

    for (int k0 = 0; k0 < K; k0 += 64) {
        __syncthreads();   // all waves done reading LDS of previous step
#pragma unroll
        for (int u = 0; u < 4; u++) {
            int ch = tid + (u << 8);          // 16B chunk id, 0..1023
            int r = ch >> 3, c8 = (ch & 7) << 3;
            int ar = m0 + r; if (ar >= M) ar = M - 1;   // per-lane global addr ok
            gload_lds16(A + (size_t)ar * K + k0 + c8, &As[ch * 8]);
            gload_lds16(W + (size_t)(n0 + r) * K + k0 + c8, &Ws[ch * 8]);
        }
        __syncthreads();   // compiler drains vmcnt before s_barrier -> staged
#pragma unroll
        for (int kk = 0; kk < 2; kk++) {
            s16x8 af[4], bf[4];
#pragma unroll
            for (int m = 0; m < 4; m++)
                af[m] = *(const s16x8*)&As[(wr * 64 + m * 16 + lr) * 64 + kk * 32 + lk * 8];
#pragma unroll
            for (int n = 0; n < 4; n++)
                bf[n] = *(const s16x8*)&Ws[(wc * 64 + n * 16 + lr) * 64 + kk * 32 + lk * 8];
#pragma unroll
            for (int m = 0; m < 4; m++)
#pragma unroll
                for (int n = 0; n < 4; n++)
                    acc[m][n] = __builtin_amdgcn_mfma_f32_16x16x32_bf16(
                        af[m], bf[n], acc[m][n], 0, 0, 0);
        }
    }

    float bv[4];
    if constexpr (!ROWBIAS) {
#pragma unroll
        for (int n = 0; n < 4; n++) bv[n] = bias[n0 + wc * 64 + n * 16 + lr];
    }
#pragma unroll
    for (int m = 0; m < 4; m++) {
#pragma unroll
        for (int j = 0; j < 4; j++) {
            int row = m0 + wr * 64 + m * 16 + lk * 4 + j;
            if (row >= M) continue;
            const float* rb = nullptr;
            if constexpr (ROWBIAS) rb = bias + (size_t)(row / L_) * N;
#pragma unroll
            for (int n = 0; n < 4; n++) {
                int col = n0 + wc * 64 + n * 16 + lr;
                float c = acc[m][n][j];
                if constexpr (ROWBIAS) c += rb[col];
                else                   c += bv[n];
                if constexpr (RELU) c = fmaxf(c, 0.0f);
                if constexpr (RESID) c += resid[(size_t)row * N + col];
                if constexpr (OUTBF) ((u16*)Cout)[(size_t)row * N + col] = f2bf(c);
                else                 ((float*)Cout)[(size_t)row * N + col] = c;
            }
        }
    }
}

// ======================================================================
// LayerNorm: one wave per row; optional ReLU; optional bf16 output.
// ======================================================================
template<int DD, bool RELU, bool OUTBF>
__global__ __launch_bounds__(256)
void ln_k(const float* __restrict__ x, const float* __restrict__ s,
          const float* __restrict__ bb, void* __restrict__ out, int M)
{
    const int lane = threadIdx.x & 63;
    const int row = (blockIdx.x << 2) + (threadIdx.x >> 6);
    if (row >= M) return;
    const float* xr = x + (size_t)row * DD;
    constexpr int NV = DD / 64;
    float v[NV];
    if constexpr (NV == 8) {
        *(float4*)(v)     = *(const float4*)(xr + lane * 8);
        *(float4*)(v + 4) = *(const float4*)(xr + lane * 8 + 4);
    } else {
        float2 t = *(const float2*)(xr + lane * 2);
        v[0] = t.x; v[1] = t.y;
    }
    float sum = 0.f, sq = 0.f;
#pragma unroll
    for (int e = 0; e < NV; e++) { sum += v[e]; sq += v[e] * v[e]; }
#pragma unroll
    for (int msk = 1; msk < 64; msk <<= 1) {
        sum += __shfl_xor(sum, msk);
        sq  += __shfl_xor(sq, msk);
    }
    const float mean = sum * (1.0f / DD);
    const float var  = sq * (1.0f / DD) - mean * mean;
    const float rstd = rsqrtf(var + EPS_);
#pragma unroll
    for (int e = 0; e < NV; e++) {
        int d = lane * NV + e;
        float r = (v[e] - mean) * rstd * s[d] + bb[d];
        if constexpr (RELU) r = fmaxf(r, 0.0f);
        v[e] = r;
    }
    if constexpr (OUTBF) {
        u16* orow = (u16*)out + (size_t)row * DD;
        if constexpr (NV == 8) {
            s16x8 o;
#pragma unroll
            for (int e = 0; e < 8; e++) o[e] = (short)f2bf(v[e]);
            *(s16x8*)(orow + lane * 8) = o;
        } else {
            orow[lane * 2] = f2bf(v[0]); orow[lane * 2 + 1] = f2bf(v[1]);
        }
    } else {
        float* orow = (float*)out + (size_t)row * DD;
        if constexpr (NV == 8) {
            *(float4*)(orow + lane * 8)     = *(float4*)(v);
            *(float4*)(orow + lane * 8 + 4) = *(float4*)(v + 4);
        } else {
            float2 t; t.x = v[0]; t.y = v[1];
            *(float2*)(orow + lane * 2) = t;
        }
    }
}

// ======================================================================
// RoPE on bf16 [BL,512] -> bf16, 8 elems/thread
// ======================================================================
__global__ __launch_bounds__(256)
void rope_k(const u16* __restrict__ n, const float* __restrict__ ct,
            const float* __restrict__ st, u16* __restrict__ r)
{
    int t = blockIdx.x * 256 + threadIdx.x;
    if (t >= BL_ * D_ / 8) return;
    int idx = t << 3;
    int l = (idx / D_) % L_;
    int d = idx & (D_ - 1);
    int dd = d & 63;
    s16x8 xv = *(const s16x8*)(n + idx);
    int pidx; float sgn;
    if (dd < 32) { pidx = idx + 32; sgn = -1.0f; }
    else         { pidx = idx - 32; sgn =  1.0f; }
    s16x8 pv = *(const s16x8*)(n + pidx);
    float4 c0 = *(const float4*)(ct + l * DH_ + dd);
    float4 c1 = *(const float4*)(ct + l * DH_ + dd + 4);
    float4 s0 = *(const float4*)(st + l * DH_ + dd);
    float4 s1 = *(const float4*)(st + l * DH_ + dd + 4);
    float cc[8] = {c0.x,c0.y,c0.z,c0.w,c1.x,c1.y,c1.z,c1.w};
    float ss[8] = {s0.x,s0.y,s0.z,s0.w,s1.x,s1.y,s1.z,s1.w};
    s16x8 o;
#pragma unroll
    for (int e = 0; e < 8; e++) {
        float xf = bf2f((u16)xv[e]);
        float pf = bf2f((u16)pv[e]);
        o[e] = (short)f2bf(xf * cc[e] + sgn * pf * ss[e]);
    }
    *(s16x8*)(r + idx) = o;
}

// ======================================================================
// MFMA flash attention with register prefetch (T14 async-stage split).
// q,k packed in qk[BL,1024] (q at col 0, k at col 512); v[BL,512].
// block = (b, h, 64-q-tile); 4 waves; per-tile pipeline:
//   barrier -> write prefetched regs to LDS -> barrier -> issue next-tile
//   global loads (hidden under compute) -> S/softmax/PV.
// ======================================================================
__global__ __launch_bounds__(256)
void attn_k(const u16* __restrict__ qk, const u16* __restrict__ v,
            const float* __restrict__ mask, u16* __restrict__ o)
{
    constexpr int LDA = 68;   // u16 stride: row step = 2 banks -> conflict-free frags
    __shared__ u16 Kt[64 * LDA];
    __shared__ u16 Vt[64 * LDA];
    __shared__ u16 Pl[64 * LDA];
    const int bh = blockIdx.x >> 4, qt = blockIdx.x & 15;
    const int b = bh >> 3, h = bh & 7;
    const int tid = threadIdx.x;
    const int lane = tid & 63, w = tid >> 6;
    const int lr = lane & 15, lg = lane >> 4;
    const size_t basebl = (size_t)b * L_;

    // Q A-fragments (row = lr within wave's 16 rows; k = 32*kk + 8*lg + e)
    const int qrow = qt * 64 + w * 16 + lr;
    const int qclamp = qrow < L_ ? qrow : L_ - 1;
    s16x8 aq[2];
#pragma unroll
    for (int kk = 0; kk < 2; kk++)
        aq[kk] = *(const s16x8*)(qk + (basebl + qclamp) * 1024 + h * DH_ + kk * 32 + lg * 8);

    // K/V tile prefetch registers
    s16x8 kreg[2], vreg[2];
    const int pch_key[2] = { tid >> 3, (tid + 256) >> 3 };
    const int pch_d8 = (tid & 7) << 3;
#pragma unroll
    for (int u = 0; u < 2; u++) {
        int gk = pch_key[u]; if (gk >= L_) gk = L_ - 1;
        kreg[u] = *(const s16x8*)(qk + (basebl + gk) * 1024 + 512 + h * DH_ + pch_d8);
        vreg[u] = *(const s16x8*)(v  + (basebl + gk) * D_ + h * DH_ + pch_d8);
    }

    f32x4 oacc[4];
    float m_run[4], l_run[4];
#pragma unroll
    for (int n = 0; n < 4; n++) oacc[n] = (f32x4)0.0f;
#pragma unroll
    for (int j = 0; j < 4; j++) { m_run[j] = -1e30f; l_run[j] = 0.f; }

    for (int kt = 0; kt < 16; kt++) {
        __syncthreads();          // all waves done reading prev Kt/Vt
        // write prefetched tile: K [key][d] vector, V^T [d][key] scalar
#pragma unroll
        for (int u = 0; u < 2; u++) {
            *(s16x8*)&Kt[pch_key[u] * LDA + pch_d8] = kreg[u];
#pragma unroll
            for (int e = 0; e < 8; e++) Vt[(pch_d8 + e) * LDA + pch_key[u]] = (u16)vreg[u][e];
        }
        __syncthreads();          // staged
        // issue next tile's global loads; vmcnt-waited at next iter's write
        if (kt < 15) {
#pragma unroll
            for (int u = 0; u < 2; u++) {
                int gk = (kt + 1) * 64 + pch_key[u]; if (gk >= L_) gk = L_ - 1;
                kreg[u] = *(const s16x8*)(qk + (basebl + gk) * 1024 + 512 + h * DH_ + pch_d8);
                vreg[u] = *(const s16x8*)(v  + (basebl + gk) * D_ + h * DH_ + pch_d8);
            }
        }

        // S = Q K^T : col = key = n*16+lr, row = q = 4*lg+j
        f32x4 sacc[4];
#pragma unroll
        for (int n = 0; n < 4; n++) {
            sacc[n] = (f32x4)0.0f;
#pragma unroll
            for (int kk = 0; kk < 2; kk++) {
                s16x8 bk = *(const s16x8*)&Kt[(n * 16 + lr) * LDA + kk * 32 + lg * 8];
                sacc[n] = __builtin_amdgcn_mfma_f32_16x16x32_bf16(aq[kk], bk, sacc[n], 0, 0, 0);
            }
        }
        bool val[4];
#pragma unroll
        for (int n = 0; n < 4; n++) {
            int key = kt * 64 + n * 16 + lr;
            val[n] = (key < L_) && (mask[basebl + key] > 0.0f);
        }
        // online softmax per j (row = 4*lg + j; 16-lane group reduce)
#pragma unroll
        for (int j = 0; j < 4; j++) {
            float sv[4];
#pragma unroll
            for (int n = 0; n < 4; n++)
                sv[n] = val[n] ? sacc[n][j] * 0.125f : -1e30f;
            float tm = fmaxf(fmaxf(sv[0], sv[1]), fmaxf(sv[2], sv[3]));
#pragma unroll
            for (int msk = 1; msk <= 8; msk <<= 1) tm = fmaxf(tm, __shfl_xor(tm, msk));
            float nm = fmaxf(m_run[j], tm);
            float corr = __expf(m_run[j] - nm);
            m_run[j] = nm;
            float p[4], ts = 0.f;
#pragma unroll
            for (int n = 0; n < 4; n++) { p[n] = __expf(sv[n] - nm); ts += p[n]; }
#pragma unroll
            for (int msk = 1; msk <= 8; msk <<= 1) ts += __shfl_xor(ts, msk);
            l_run[j] = l_run[j] * corr + ts;
#pragma unroll
            for (int n = 0; n < 4; n++) {
                oacc[n][j] *= corr;
                Pl[(w * 16 + lg * 4 + j) * LDA + n * 16 + lr] = f2bf(p[n]);
            }
        }
        // PV (wave-private P rows: intra-wave LDS dep, no barrier needed)
#pragma unroll
        for (int kk = 0; kk < 2; kk++) {
            s16x8 ap = *(const s16x8*)&Pl[(w * 16 + lr) * LDA + kk * 32 + lg * 8];
#pragma unroll
            for (int n = 0; n < 4; n++) {
                s16x8 bv = *(const s16x8*)&Vt[(n * 16 + lr) * LDA + kk * 32 + lg * 8];
                oacc[n] = __builtin_amdgcn_mfma_f32_16x16x32_bf16(ap, bv, oacc[n], 0, 0, 0);
            }
        }
    }

    // epilogue: rows q = qt*64 + w*16 + 4*lg + j, cols d = n*16 + lr
#pragma unroll
    for (int j = 0; j < 4; j++) {
        int qr = qt * 64 + w * 16 + lg * 4 + j;
        if (qr >= L_) continue;
        float inv = 1.0f / l_run[j];
#pragma unroll
        for (int n = 0; n < 4; n++)
            o[(basebl + qr) * D_ + h * DH_ + n * 16 + lr] = f2bf(oacc[n][j] * inv);
    }
}

// ======================================================================
// masked mean pool over L
// ======================================================================
__global__ __launch_bounds__(512)
void pool_k(const float* __restrict__ x, const float* __restrict__ mask,
             float* __restrict__ g)
{
    const int b = blockIdx.x;
    const int d = threadIdx.x;
    float acc = 0.f, ms = 0.f;
    for (int l = 0; l < L_; l++) {
        float mv = mask[b * L_ + l];
        acc += x[((size_t)b * L_ + l) * D_ + d] * mv;
        ms += mv;
    }
    g[b * D_ + d] = acc / ms;
}

// ======================================================================
// gpart[b][j] = h1_b[j] + dot(gctx[b], h1_w[j, 512:1024])  (fp32)
// ======================================================================
__global__ __launch_bounds__(256)
void gpart_k(const float* __restrict__ g, const float* __restrict__ h1w,
             const float* __restrict__ h1b, float* __restrict__ gp)
{
    const int lane = threadIdx.x & 63;
    const int gid = (blockIdx.x << 2) + (threadIdx.x >> 6);
    const int b = gid >> 7, j = gid & 127;
    const float* wr = h1w + (size_t)j * (2 * D_) + D_;
    const float* gr = g + b * D_;
    float4 a0 = *(const float4*)(gr + lane * 8);
    float4 a1 = *(const float4*)(gr + lane * 8 + 4);
    float4 w0 = *(const float4*)(wr + lane * 8);
    float4 w1v = *(const float4*)(wr + lane * 8 + 4);
    float acc = a0.x * w0.x + a0.y * w0.y + a0.z * w0.z + a0.w * w0.w
              + a1.x * w1v.x + a1.y * w1v.y + a1.z * w1v.z + a1.w * w1v.w;
#pragma unroll
    for (int msk = 1; msk < 64; msk <<= 1) acc += __shfl_xor(acc, msk);
    if (lane == 0) gp[b * 128 + j] = acc + h1b[j];
}

// ======================================================================
// logits[m] = h2_b + dot(h[m,0:128], h2_w)
// ======================================================================
__global__ __launch_bounds__(256)
void logits_k(const float* __restrict__ h, const float* __restrict__ w,
              const float* __restrict__ bsc, float* __restrict__ out, int M)
{
    const int lane = threadIdx.x & 63;
    const int row = (blockIdx.x << 2) + (threadIdx.x >> 6);
    if (row >= M) return;
    float2 hv = *(const float2*)(h + (size_t)row * 128 + lane * 2);
    float2 wv = *(const float2*)(w + lane * 2);
    float acc = hv.x * wv.x + hv.y * wv.y;
#pragma unroll
    for (int msk = 1; msk < 64; msk <<= 1) acc += __shfl_xor(acc, msk);
    if (lane == 0) out[row] = acc + bsc[0];
}

// ======================================================================
// host orchestration
// ======================================================================
extern "C" void kernel_launch(void* const* d_in, const int* in_sizes, int n_in,
                              void* d_out, int out_size, void* d_ws, size_t ws_size,
                              hipStream_t stream)
{
    const float* emb       = (const float*)d_in[0];
    const float* mask      = (const float*)d_in[1];
    const float* proj_w    = (const float*)d_in[3];
    const float* proj_b    = (const float*)d_in[4];
    const float* proj_ln_s = (const float*)d_in[5];
    const float* proj_ln_b = (const float*)d_in[6];
    const float* ln1_s     = (const float*)d_in[7];
    const float* ln1_b     = (const float*)d_in[8];
    const float* in_w      = (const float*)d_in[9];
    const float* in_b      = (const float*)d_in[10];
    const float* out_w     = (const float*)d_in[11];
    const float* out_b     = (const float*)d_in[12];
    const float* ln2_s     = (const float*)d_in[13];
    const float* ln2_b     = (const float*)d_in[14];
    const float* w1        = (const float*)d_in[15];
    const float* b1        = (const float*)d_in[16];
    const float* w2        = (const float*)d_in[17];
    const float* b2        = (const float*)d_in[18];
    const float* h1_w      = (const float*)d_in[19];
    const float* h1_b      = (const float*)d_in[20];
    const float* hln_s     = (const float*)d_in[21];
    const float* hln_b     = (const float*)d_in[22];
    const float* h2_w      = (const float*)d_in[23];
    const float* h2_b      = (const float*)d_in[24];
    float* out = (float*)d_out;

    // Workspace map (S = BL*D floats):
    //   [0,S)      X fp32 residual
    //   [S,2S)     Rf fp32 (proj-out, head Hb) / QKB bf16 [BL,1024] (disjoint)
    //   [2S,2.5S)  VB bf16
    //   [2.5S,3S)  NbB bf16
    //   [3S,5S)    FFb16 bf16 [BL,2048]; aliases embB [3S,4.25S), RopeB
    //              [3S,3.5S), RB [4S,4.5S) -- all time-disjoint
    //   [5S,...)   bf16 weights, CT/ST/GC/GP
    float* ws = (float*)d_ws;
    const size_t S = (size_t)BL_ * D_;
    float* X  = ws;
    float* Rf = ws + S;
    u16* QKB   = (u16*)(ws + S);           // [BL,1024] bf16 = [S,2S) floats
    u16* VB    = (u16*)(ws + 2 * S);
    u16* NbB   = (u16*)(ws + 2 * S) + S;
    u16* FFb16 = (u16*)(ws + 3 * S);
    u16* RopeB = FFb16;
    u16* embB  = FFb16;
    u16* RB    = (u16*)(ws + 4 * S);
    u16* projwB = (u16*)(ws + 5 * S);
    u16* iwB  = projwB + 512 * 1280;
    u16* owB  = iwB + (size_t)NL_ * 3 * D_ * D_;
    u16* w1B  = owB + (size_t)NL_ * D_ * D_;
    u16* w2B  = w1B + (size_t)NL_ * FF_ * D_;
    u16* h1wB = w2B + (size_t)NL_ * D_ * FF_;
    float* CT = ws + 5 * S + 6651904;
    float* ST = CT + L_ * DH_;
    float* GC = ST + L_ * DH_;
    float* GP = GC + B_ * D_;
    float* Hb = Rf;

    const int MT = 128;
    const dim3 blk(256);
    const int lnGrid = (BL_ + 3) / 4;

    cast_k<<<(BL_ * E_ / 8 + 255) / 256, blk, 0, stream>>>(emb, embB, BL_ * E_ / 8);
    cast_k<<<(512 * 1280 / 8 + 255) / 256, blk, 0, stream>>>(proj_w, projwB, 512 * 1280 / 8);
    cast_k<<<(NL_ * 3 * D_ * D_ / 8 + 255) / 256, blk, 0, stream>>>(in_w, iwB, NL_ * 3 * D_ * D_ / 8);
    cast_k<<<(NL_ * D_ * D_ / 8 + 255) / 256, blk, 0, stream>>>(out_w, owB, NL_ * D_ * D_ / 8);
    cast_k<<<(NL_ * FF_ * D_ / 8 + 255) / 256, blk, 0, stream>>>(w1, w1B, NL_ * FF_ * D_ / 8);
    cast_k<<<(NL_ * D_ * FF_ / 8 + 255) / 256, blk, 0, stream>>>(w2, w2B, NL_ * D_ * FF_ / 8);
    h1cast_k<<<(128 * 512 / 8 + 255) / 256, blk, 0, stream>>>(h1_w, h1wB);
    tables_k<<<(L_ * DH_ + 255) / 256, blk, 0, stream>>>(CT, ST);

    mgemm_k<false,false,false,false><<<MT * (D_ / 128), blk, 0, stream>>>(
        embB, projwB, proj_b, nullptr, Rf, BL_, D_, E_);
    ln_k<D_,false,false><<<lnGrid, blk, 0, stream>>>(Rf, proj_ln_s, proj_ln_b, X, BL_);

    for (int i = 0; i < NL_; i++) {
        const u16* iw = iwB + (size_t)i * 3 * D_ * D_;
        const float* ib = in_b + (size_t)i * 3 * D_;
        ln_k<D_,false,true><<<lnGrid, blk, 0, stream>>>(X, ln1_s + i * D_, ln1_b + i * D_, NbB, BL_);
        mgemm_k<false,false,true,false><<<MT * 4, blk, 0, stream>>>(
            NbB, iw + 2 * D_ * D_, ib + 2 * D_, nullptr, VB, BL_, D_, D_);
        rope_k<<<(BL_ * D_ / 8 + 255) / 256, blk, 0, stream>>>(NbB, CT, ST, RopeB);
        // fused q+k projection: W rows [wq;wk], bias [bq;bk], N=1024 -> QKB
        mgemm_k<false,false,true,false><<<MT * 8, blk, 0, stream>>>(
            RopeB, iw, ib, nullptr, QKB, BL_, 1024, D_);
        attn_k<<<B_ * H_ * 16, blk, 0, stream>>>(QKB, VB, mask, RB);
        mgemm_k<false,true,false,false><<<MT * 4, blk, 0, stream>>>(
            RB, owB + (size_t)i * D_ * D_, out_b + i * D_, X, X, BL_, D_, D_);
        ln_k<D_,false,true><<<lnGrid, blk, 0, stream>>>(X, ln2_s + i * D_, ln2_b + i * D_, NbB, BL_);
        mgemm_k<true,false,true,false><<<MT * 16, blk, 0, stream>>>(
            NbB, w1B + (size_t)i * FF_ * D_, b1 + i * FF_, nullptr, FFb16, BL_, FF_, D_);
        mgemm_k<false,true,false,false><<<MT * 4, blk, 0, stream>>>(
            FFb16, w2B + (size_t)i * D_ * FF_, b2 + i * D_, X, X, BL_, D_, FF_);
    }

    pool_k<<<B_, dim3(512), 0, stream>>>(X, mask, GC);
    gpart_k<<<(B_ * 128) / 4, blk, 0, stream>>>(GC, h1_w, h1_b, GP);
    cast_k<<<(int)((S / 8 + 255) / 256), blk, 0, stream>>>(X, NbB, (int)(S / 8));
    mgemm_k<false,false,false,true><<<MT * 1, blk, 0, stream>>>(
        NbB, h1wB, GP, nullptr, Hb, BL_, 128, D_);
    ln_k<128,true,false><<<lnGrid, blk, 0, stream>>>(Hb, hln_s, hln_b, Hb, BL_);
    logits_k<<<lnGrid, blk, 0, stream>>>(Hb, h2_w, h2_b, out, BL_);
}

// Round 7
// 1575.650 us; speedup vs baseline: 1.0820x; 1.0820x over previous
//
#include <hip/hip_runtime.h>
#include <cstdint>
#include <cstddef>

// ---------------- problem constants ----------------
#define B_   16
#define L_   1022
#define E_   1280
#define D_   512
#define H_   8
#define FF_  2048
#define NL_  4
#define DH_  64
#define BL_  (B_*L_)      // 16352
#define EPS_ 1e-5f

typedef unsigned short u16;
typedef unsigned int   u32;
typedef float f32x4 __attribute__((ext_vector_type(4)));
typedef short s16x8 __attribute__((ext_vector_type(8)));

__device__ __forceinline__ u16 f2bf(float f) {
    u32 u = __builtin_bit_cast(u32, f);
    u += 0x7fffu + ((u >> 16) & 1u);
    return (u16)(u >> 16);
}
__device__ __forceinline__ float bf2f(u16 u) {
    return __builtin_bit_cast(float, (u32)u << 16);
}

// ======================================================================
// fp32 -> bf16 cast, 8 elems/thread
// ======================================================================
__global__ __launch_bounds__(256)
void cast_k(const float* __restrict__ src, u16* __restrict__ dst, int n8) {
    int t = blockIdx.x * 256 + threadIdx.x;
    if (t >= n8) return;
    const float* s = src + (size_t)t * 8;
    float4 a = *(const float4*)(s);
    float4 b = *(const float4*)(s + 4);
    s16x8 o;
    o[0] = (short)f2bf(a.x); o[1] = (short)f2bf(a.y);
    o[2] = (short)f2bf(a.z); o[3] = (short)f2bf(a.w);
    o[4] = (short)f2bf(b.x); o[5] = (short)f2bf(b.y);
    o[6] = (short)f2bf(b.z); o[7] = (short)f2bf(b.w);
    *(s16x8*)(dst + (size_t)t * 8) = o;
}

// h1_w left half [128, 0:512] (row stride 1024) -> packed bf16 [128,512]
__global__ __launch_bounds__(256)
void h1cast_k(const float* __restrict__ src, u16* __restrict__ dst) {
    int t = blockIdx.x * 256 + threadIdx.x;
    if (t >= 128 * 512 / 8) return;
    int row = t >> 6, c8 = (t & 63) << 3;
    const float* s = src + (size_t)row * 1024 + c8;
    float4 a = *(const float4*)(s);
    float4 b = *(const float4*)(s + 4);
    s16x8 o;
    o[0] = (short)f2bf(a.x); o[1] = (short)f2bf(a.y);
    o[2] = (short)f2bf(a.z); o[3] = (short)f2bf(a.w);
    o[4] = (short)f2bf(b.x); o[5] = (short)f2bf(b.y);
    o[6] = (short)f2bf(b.z); o[7] = (short)f2bf(b.w);
    *(s16x8*)(dst + (size_t)row * 512 + c8) = o;
}

// ======================================================================
// RoPE cos/sin tables
// ======================================================================
__global__ void tables_k(float* __restrict__ ct, float* __restrict__ st) {
    int idx = blockIdx.x * blockDim.x + threadIdx.x;
    if (idx >= L_ * DH_) return;
    int l = idx / DH_;
    int d = idx % DH_;
    int j = d & 31;
    float invf = powf(10000.0f, -(float)(2 * j) / (float)DH_);
    float ang = (float)l * invf;
    ct[idx] = cosf(ang);
    st[idx] = sinf(ang);
}

// ======================================================================
// bf16 MFMA GEMM (reg-staged, r5-proven): C = act(A @ W^T + bias)(+resid)
// 128x128 tile, BK=64, 256 threads (4 waves 2x2), 4x4 16x16 frags/wave.
// ======================================================================
template<bool RELU, bool RESID, bool OUTBF, bool ROWBIAS>
__global__ __launch_bounds__(256)
void mgemm_k(const u16* __restrict__ A, const u16* __restrict__ W,
             const float* __restrict__ bias, const float* __restrict__ resid,
             void* __restrict__ Cout, int M, int N, int K)
{
    constexpr int LDT = 72;               // padded LDS row stride (bf16)
    __shared__ u16 As[128 * LDT];
    __shared__ u16 Ws[128 * LDT];
    const int nt = N >> 7;
    const int bx = blockIdx.x % nt;
    const int by = blockIdx.x / nt;
    const int m0 = by << 7, n0 = bx << 7;
    const int tid = threadIdx.x;
    const int lane = tid & 63, wid = tid >> 6;
    const int wr = wid >> 1, wc = wid & 1;
    const int lr = lane & 15, lk = lane >> 4;

    f32x4 acc[4][4];
#pragma unroll
    for (int m = 0; m < 4; m++)
#pragma unroll
        for (int n = 0; n < 4; n++) acc[m][n] = (f32x4)0.0f;

    for (int k0 = 0; k0 < K; k0 += 64) {
        s16x8 va[4], vw[4];
#pragma unroll
        for (int u = 0; u < 4; u++) {
            int ch = tid + (u << 8);          // 16B chunk id, 0..1023
            int r = ch >> 3, c8 = (ch & 7) << 3;
            int ar = m0 + r; if (ar >= M) ar = M - 1;
            va[u] = *(const s16x8*)(A + (size_t)ar * K + k0 + c8);
            vw[u] = *(const s16x8*)(W + (size_t)(n0 + r) * K + k0 + c8);
        }
        __syncthreads();   // previous iteration's LDS reads complete
#pragma unroll
        for (int u = 0; u < 4; u++) {
            int ch = tid + (u << 8);
            int r = ch >> 3, c8 = (ch & 7) << 3;
            *(s16x8*)&As[r * LDT + c8] = va[u];
            *(s16x8*)&Ws[r * LDT + c8] = vw[u];
        }
        __syncthreads();   // tiles staged
#pragma unroll
        for (int kk = 0; kk < 2; kk++) {
            s16x8 af[4], bf[4];
#pragma unroll
            for (int m = 0; m < 4; m++)
                af[m] = *(const s16x8*)&As[(wr * 64 + m * 16 + lr) * LDT + kk * 32 + lk * 8];
#pragma unroll
            for (int n = 0; n < 4; n++)
                bf[n] = *(const s16x8*)&Ws[(wc * 64 + n * 16 + lr) * LDT + kk * 32 + lk * 8];
#pragma unroll
            for (int m = 0; m < 4; m++)
#pragma unroll
                for (int n = 0; n < 4; n++)
                    acc[m][n] = __builtin_amdgcn_mfma_f32_16x16x32_bf16(
                        af[m], bf[n], acc[m][n], 0, 0, 0);
        }
    }

    float bv[4];
    if constexpr (!ROWBIAS) {
#pragma unroll
        for (int n = 0; n < 4; n++) bv[n] = bias[n0 + wc * 64 + n * 16 + lr];
    }
#pragma unroll
    for (int m = 0; m < 4; m++) {
#pragma unroll
        for (int j = 0; j < 4; j++) {
            int row = m0 + wr * 64 + m * 16 + lk * 4 + j;
            if (row >= M) continue;
            const float* rb = nullptr;
            if constexpr (ROWBIAS) rb = bias + (size_t)(row / L_) * N;
#pragma unroll
            for (int n = 0; n < 4; n++) {
                int col = n0 + wc * 64 + n * 16 + lr;
                float c = acc[m][n][j];
                if constexpr (ROWBIAS) c += rb[col];
                else                   c += bv[n];
                if constexpr (RELU) c = fmaxf(c, 0.0f);
                if constexpr (RESID) c += resid[(size_t)row * N + col];
                if constexpr (OUTBF) ((u16*)Cout)[(size_t)row * N + col] = f2bf(c);
                else                 ((float*)Cout)[(size_t)row * N + col] = c;
            }
        }
    }
}

// ======================================================================
// LayerNorm: one wave per row; optional ReLU; optional bf16 output.
// ======================================================================
template<int DD, bool RELU, bool OUTBF>
__global__ __launch_bounds__(256)
void ln_k(const float* __restrict__ x, const float* __restrict__ s,
          const float* __restrict__ bb, void* __restrict__ out, int M)
{
    const int lane = threadIdx.x & 63;
    const int row = (blockIdx.x << 2) + (threadIdx.x >> 6);
    if (row >= M) return;
    const float* xr = x + (size_t)row * DD;
    constexpr int NV = DD / 64;
    float v[NV];
    if constexpr (NV == 8) {
        *(float4*)(v)     = *(const float4*)(xr + lane * 8);
        *(float4*)(v + 4) = *(const float4*)(xr + lane * 8 + 4);
    } else {
        float2 t = *(const float2*)(xr + lane * 2);
        v[0] = t.x; v[1] = t.y;
    }
    float sum = 0.f, sq = 0.f;
#pragma unroll
    for (int e = 0; e < NV; e++) { sum += v[e]; sq += v[e] * v[e]; }
#pragma unroll
    for (int msk = 1; msk < 64; msk <<= 1) {
        sum += __shfl_xor(sum, msk);
        sq  += __shfl_xor(sq, msk);
    }
    const float mean = sum * (1.0f / DD);
    const float var  = sq * (1.0f / DD) - mean * mean;
    const float rstd = rsqrtf(var + EPS_);
#pragma unroll
    for (int e = 0; e < NV; e++) {
        int d = lane * NV + e;
        float r = (v[e] - mean) * rstd * s[d] + bb[d];
        if constexpr (RELU) r = fmaxf(r, 0.0f);
        v[e] = r;
    }
    if constexpr (OUTBF) {
        u16* orow = (u16*)out + (size_t)row * DD;
        if constexpr (NV == 8) {
            s16x8 o;
#pragma unroll
            for (int e = 0; e < 8; e++) o[e] = (short)f2bf(v[e]);
            *(s16x8*)(orow + lane * 8) = o;
        } else {
            orow[lane * 2] = f2bf(v[0]); orow[lane * 2 + 1] = f2bf(v[1]);
        }
    } else {
        float* orow = (float*)out + (size_t)row * DD;
        if constexpr (NV == 8) {
            *(float4*)(orow + lane * 8)     = *(float4*)(v);
            *(float4*)(orow + lane * 8 + 4) = *(float4*)(v + 4);
        } else {
            float2 t; t.x = v[0]; t.y = v[1];
            *(float2*)(orow + lane * 2) = t;
        }
    }
}

// ======================================================================
// RoPE on bf16 [BL,512] -> bf16, 8 elems/thread
// ======================================================================
__global__ __launch_bounds__(256)
void rope_k(const u16* __restrict__ n, const float* __restrict__ ct,
            const float* __restrict__ st, u16* __restrict__ r)
{
    int t = blockIdx.x * 256 + threadIdx.x;
    if (t >= BL_ * D_ / 8) return;
    int idx = t << 3;
    int l = (idx / D_) % L_;
    int d = idx & (D_ - 1);
    int dd = d & 63;
    s16x8 xv = *(const s16x8*)(n + idx);
    int pidx; float sgn;
    if (dd < 32) { pidx = idx + 32; sgn = -1.0f; }
    else         { pidx = idx - 32; sgn =  1.0f; }
    s16x8 pv = *(const s16x8*)(n + pidx);
    float4 c0 = *(const float4*)(ct + l * DH_ + dd);
    float4 c1 = *(const float4*)(ct + l * DH_ + dd + 4);
    float4 s0 = *(const float4*)(st + l * DH_ + dd);
    float4 s1 = *(const float4*)(st + l * DH_ + dd + 4);
    float cc[8] = {c0.x,c0.y,c0.z,c0.w,c1.x,c1.y,c1.z,c1.w};
    float ss[8] = {s0.x,s0.y,s0.z,s0.w,s1.x,s1.y,s1.z,s1.w};
    s16x8 o;
#pragma unroll
    for (int e = 0; e < 8; e++) {
        float xf = bf2f((u16)xv[e]);
        float pf = bf2f((u16)pv[e]);
        o[e] = (short)f2bf(xf * cc[e] + sgn * pf * ss[e]);
    }
    *(s16x8*)(r + idx) = o;
}

// ======================================================================
// MFMA flash attention, QBLK=128 (bf16 in/out, fp32 softmax+accum).
// q,k packed qk[BL,1024] (q col 0, k col 512); v[BL,512].
// block = (b, h, 128-q-tile); 4 waves; wave owns 2 groups of 16 q-rows.
// Per 64-key tile: K LDS [key][d], V^T LDS [d][key], P bf16 wave-private.
// Softmax denominator = extra ones-column MFMA accumulator (no sum-shfl).
// ======================================================================
__global__ __launch_bounds__(256)
void attn_k(const u16* __restrict__ qk, const u16* __restrict__ v,
            const float* __restrict__ mask, u16* __restrict__ o)
{
    constexpr int LDA = 68;
    __shared__ u16 Kt[64 * LDA];
    __shared__ u16 Vt[64 * LDA];
    __shared__ u16 Pl[64 * LDA];   // 16 rows per wave
    const int bh = blockIdx.x >> 3, qt = blockIdx.x & 7;
    const int b = bh >> 3, h = bh & 7;
    const int tid = threadIdx.x;
    const int lane = tid & 63, w = tid >> 6;
    const int lr = lane & 15, lg = lane >> 4;
    const size_t basebl = (size_t)b * L_;

    // Q A-frags: rows qt*128 + w*32 + g*16 + lr; k = 32*kk + 8*lg + e
    s16x8 aq[2][2];
#pragma unroll
    for (int g = 0; g < 2; g++) {
        int qrow = qt * 128 + w * 32 + g * 16 + lr;
        int qc = qrow < L_ ? qrow : L_ - 1;
#pragma unroll
        for (int kk = 0; kk < 2; kk++)
            aq[g][kk] = *(const s16x8*)(qk + (basebl + qc) * 1024 + h * DH_ + kk * 32 + lg * 8);
    }

    s16x8 bones;
#pragma unroll
    for (int e = 0; e < 8; e++) bones[e] = (short)0x3F80;   // bf16 1.0

    f32x4 oacc[2][4], ocs[2];
    float m_run[2][4];
#pragma unroll
    for (int g = 0; g < 2; g++) {
        ocs[g] = (f32x4)0.0f;
#pragma unroll
        for (int n = 0; n < 4; n++) oacc[g][n] = (f32x4)0.0f;
#pragma unroll
        for (int j = 0; j < 4; j++) m_run[g][j] = -1e30f;
    }

    const int st_key = tid >> 3;          // 0..31 (u=1 adds 32)
    const int st_d8 = (tid & 7) << 3;

    for (int kt = 0; kt < 16; kt++) {
        __syncthreads();          // all waves done reading prev Kt/Vt
#pragma unroll
        for (int u = 0; u < 2; u++) {
            int key = st_key + u * 32;
            int gk = kt * 64 + key; if (gk >= L_) gk = L_ - 1;
            s16x8 kv = *(const s16x8*)(qk + (basebl + gk) * 1024 + 512 + h * DH_ + st_d8);
            s16x8 vv = *(const s16x8*)(v  + (basebl + gk) * D_ + h * DH_ + st_d8);
            *(s16x8*)&Kt[key * LDA + st_d8] = kv;
#pragma unroll
            for (int e = 0; e < 8; e++) Vt[(st_d8 + e) * LDA + key] = (u16)vv[e];
        }
        __syncthreads();

        bool val[4];
#pragma unroll
        for (int n = 0; n < 4; n++) {
            int key = kt * 64 + n * 16 + lr;
            val[n] = (key < L_) && (mask[basebl + key] > 0.0f);
        }

#pragma unroll
        for (int g = 0; g < 2; g++) {
            // S = Q K^T : col = key = n*16+lr, row = q = 4*lg+j
            f32x4 sacc[4];
#pragma unroll
            for (int n = 0; n < 4; n++) {
                sacc[n] = (f32x4)0.0f;
#pragma unroll
                for (int kk = 0; kk < 2; kk++) {
                    s16x8 bk = *(const s16x8*)&Kt[(n * 16 + lr) * LDA + kk * 32 + lg * 8];
                    sacc[n] = __builtin_amdgcn_mfma_f32_16x16x32_bf16(aq[g][kk], bk, sacc[n], 0, 0, 0);
                }
            }
            // online softmax per j (max via 16-lane shfl; sum via ones-MFMA)
#pragma unroll
            for (int j = 0; j < 4; j++) {
                float sv[4];
#pragma unroll
                for (int n = 0; n < 4; n++)
                    sv[n] = val[n] ? sacc[n][j] * 0.125f : -1e30f;
                float tm = fmaxf(fmaxf(sv[0], sv[1]), fmaxf(sv[2], sv[3]));
#pragma unroll
                for (int msk = 1; msk <= 8; msk <<= 1) tm = fmaxf(tm, __shfl_xor(tm, msk));
                float nm = fmaxf(m_run[g][j], tm);
                float corr = __expf(m_run[g][j] - nm);
                m_run[g][j] = nm;
                ocs[g][j] *= corr;
#pragma unroll
                for (int n = 0; n < 4; n++) {
                    oacc[g][n][j] *= corr;
                    Pl[(w * 16 + lg * 4 + j) * LDA + n * 16 + lr] = f2bf(__expf(sv[n] - nm));
                }
            }
            // PV + denominator (wave-private P rows: intra-wave dep only)
#pragma unroll
            for (int kk = 0; kk < 2; kk++) {
                s16x8 ap = *(const s16x8*)&Pl[(w * 16 + lr) * LDA + kk * 32 + lg * 8];
#pragma unroll
                for (int n = 0; n < 4; n++) {
                    s16x8 bv = *(const s16x8*)&Vt[(n * 16 + lr) * LDA + kk * 32 + lg * 8];
                    oacc[g][n] = __builtin_amdgcn_mfma_f32_16x16x32_bf16(ap, bv, oacc[g][n], 0, 0, 0);
                }
                ocs[g] = __builtin_amdgcn_mfma_f32_16x16x32_bf16(ap, bones, ocs[g], 0, 0, 0);
            }
        }
    }

    // epilogue: rows q = qt*128 + w*32 + g*16 + 4*lg + j, cols d = n*16+lr
#pragma unroll
    for (int g = 0; g < 2; g++) {
#pragma unroll
        for (int j = 0; j < 4; j++) {
            int qr = qt * 128 + w * 32 + g * 16 + lg * 4 + j;
            if (qr >= L_) continue;
            float inv = 1.0f / ocs[g][j];
#pragma unroll
            for (int n = 0; n < 4; n++)
                o[(basebl + qr) * D_ + h * DH_ + n * 16 + lr] = f2bf(oacc[g][n][j] * inv);
        }
    }
}

// ======================================================================
// masked mean pool over L
// ======================================================================
__global__ __launch_bounds__(512)
void pool_k(const float* __restrict__ x, const float* __restrict__ mask,
             float* __restrict__ g)
{
    const int b = blockIdx.x;
    const int d = threadIdx.x;
    float acc = 0.f, ms = 0.f;
    for (int l = 0; l < L_; l++) {
        float mv = mask[b * L_ + l];
        acc += x[((size_t)b * L_ + l) * D_ + d] * mv;
        ms += mv;
    }
    g[b * D_ + d] = acc / ms;
}

// ======================================================================
// gpart[b][j] = h1_b[j] + dot(gctx[b], h1_w[j, 512:1024])  (fp32)
// ======================================================================
__global__ __launch_bounds__(256)
void gpart_k(const float* __restrict__ g, const float* __restrict__ h1w,
             const float* __restrict__ h1b, float* __restrict__ gp)
{
    const int lane = threadIdx.x & 63;
    const int gid = (blockIdx.x << 2) + (threadIdx.x >> 6);
    const int b = gid >> 7, j = gid & 127;
    const float* wr = h1w + (size_t)j * (2 * D_) + D_;
    const float* gr = g + b * D_;
    float4 a0 = *(const float4*)(gr + lane * 8);
    float4 a1 = *(const float4*)(gr + lane * 8 + 4);
    float4 w0 = *(const float4*)(wr + lane * 8);
    float4 w1v = *(const float4*)(wr + lane * 8 + 4);
    float acc = a0.x * w0.x + a0.y * w0.y + a0.z * w0.z + a0.w * w0.w
              + a1.x * w1v.x + a1.y * w1v.y + a1.z * w1v.z + a1.w * w1v.w;
#pragma unroll
    for (int msk = 1; msk < 64; msk <<= 1) acc += __shfl_xor(acc, msk);
    if (lane == 0) gp[b * 128 + j] = acc + h1b[j];
}

// ======================================================================
// logits[m] = h2_b + dot(h[m,0:128], h2_w)
// ======================================================================
__global__ __launch_bounds__(256)
void logits_k(const float* __restrict__ h, const float* __restrict__ w,
              const float* __restrict__ bsc, float* __restrict__ out, int M)
{
    const int lane = threadIdx.x & 63;
    const int row = (blockIdx.x << 2) + (threadIdx.x >> 6);
    if (row >= M) return;
    float2 hv = *(const float2*)(h + (size_t)row * 128 + lane * 2);
    float2 wv = *(const float2*)(w + lane * 2);
    float acc = hv.x * wv.x + hv.y * wv.y;
#pragma unroll
    for (int msk = 1; msk < 64; msk <<= 1) acc += __shfl_xor(acc, msk);
    if (lane == 0) out[row] = acc + bsc[0];
}

// ======================================================================
// host orchestration
// ======================================================================
extern "C" void kernel_launch(void* const* d_in, const int* in_sizes, int n_in,
                              void* d_out, int out_size, void* d_ws, size_t ws_size,
                              hipStream_t stream)
{
    const float* emb       = (const float*)d_in[0];
    const float* mask      = (const float*)d_in[1];
    const float* proj_w    = (const float*)d_in[3];
    const float* proj_b    = (const float*)d_in[4];
    const float* proj_ln_s = (const float*)d_in[5];
    const float* proj_ln_b = (const float*)d_in[6];
    const float* ln1_s     = (const float*)d_in[7];
    const float* ln1_b     = (const float*)d_in[8];
    const float* in_w      = (const float*)d_in[9];
    const float* in_b      = (const float*)d_in[10];
    const float* out_w     = (const float*)d_in[11];
    const float* out_b     = (const float*)d_in[12];
    const float* ln2_s     = (const float*)d_in[13];
    const float* ln2_b     = (const float*)d_in[14];
    const float* w1        = (const float*)d_in[15];
    const float* b1        = (const float*)d_in[16];
    const float* w2        = (const float*)d_in[17];
    const float* b2        = (const float*)d_in[18];
    const float* h1_w      = (const float*)d_in[19];
    const float* h1_b      = (const float*)d_in[20];
    const float* hln_s     = (const float*)d_in[21];
    const float* hln_b     = (const float*)d_in[22];
    const float* h2_w      = (const float*)d_in[23];
    const float* h2_b      = (const float*)d_in[24];
    float* out = (float*)d_out;

    // Workspace map (S = BL*D floats):
    //   [0,S)      X fp32 residual
    //   [S,2S)     Rf fp32 (proj-out, head Hb) / QKB bf16 [BL,1024] (disjoint)
    //   [2S,2.5S)  VB bf16
    //   [2.5S,3S)  NbB bf16
    //   [3S,5S)    FFb16 bf16 [BL,2048]; aliases embB [3S,4.25S), RopeB
    //              [3S,3.5S), RB [4S,4.5S) -- all time-disjoint
    //   [5S,...)   bf16 weights, CT/ST/GC/GP
    float* ws = (float*)d_ws;
    const size_t S = (size_t)BL_ * D_;
    float* X  = ws;
    float* Rf = ws + S;
    u16* QKB   = (u16*)(ws + S);           // [BL,1024] bf16 = [S,2S) floats
    u16* VB    = (u16*)(ws + 2 * S);
    u16* NbB   = (u16*)(ws + 2 * S) + S;
    u16* FFb16 = (u16*)(ws + 3 * S);
    u16* RopeB = FFb16;
    u16* embB  = FFb16;
    u16* RB    = (u16*)(ws + 4 * S);
    u16* projwB = (u16*)(ws + 5 * S);
    u16* iwB  = projwB + 512 * 1280;
    u16* owB  = iwB + (size_t)NL_ * 3 * D_ * D_;
    u16* w1B  = owB + (size_t)NL_ * D_ * D_;
    u16* w2B  = w1B + (size_t)NL_ * FF_ * D_;
    u16* h1wB = w2B + (size_t)NL_ * D_ * FF_;
    float* CT = ws + 5 * S + 6651904;
    float* ST = CT + L_ * DH_;
    float* GC = ST + L_ * DH_;
    float* GP = GC + B_ * D_;
    float* Hb = Rf;

    const int MT = 128;
    const dim3 blk(256);
    const int lnGrid = (BL_ + 3) / 4;

    cast_k<<<(BL_ * E_ / 8 + 255) / 256, blk, 0, stream>>>(emb, embB, BL_ * E_ / 8);
    cast_k<<<(512 * 1280 / 8 + 255) / 256, blk, 0, stream>>>(proj_w, projwB, 512 * 1280 / 8);
    cast_k<<<(NL_ * 3 * D_ * D_ / 8 + 255) / 256, blk, 0, stream>>>(in_w, iwB, NL_ * 3 * D_ * D_ / 8);
    cast_k<<<(NL_ * D_ * D_ / 8 + 255) / 256, blk, 0, stream>>>(out_w, owB, NL_ * D_ * D_ / 8);
    cast_k<<<(NL_ * FF_ * D_ / 8 + 255) / 256, blk, 0, stream>>>(w1, w1B, NL_ * FF_ * D_ / 8);
    cast_k<<<(NL_ * D_ * FF_ / 8 + 255) / 256, blk, 0, stream>>>(w2, w2B, NL_ * D_ * FF_ / 8);
    h1cast_k<<<(128 * 512 / 8 + 255) / 256, blk, 0, stream>>>(h1_w, h1wB);
    tables_k<<<(L_ * DH_ + 255) / 256, blk, 0, stream>>>(CT, ST);

    mgemm_k<false,false,false,false><<<MT * (D_ / 128), blk, 0, stream>>>(
        embB, projwB, proj_b, nullptr, Rf, BL_, D_, E_);
    ln_k<D_,false,false><<<lnGrid, blk, 0, stream>>>(Rf, proj_ln_s, proj_ln_b, X, BL_);

    for (int i = 0; i < NL_; i++) {
        const u16* iw = iwB + (size_t)i * 3 * D_ * D_;
        const float* ib = in_b + (size_t)i * 3 * D_;
        ln_k<D_,false,true><<<lnGrid, blk, 0, stream>>>(X, ln1_s + i * D_, ln1_b + i * D_, NbB, BL_);
        mgemm_k<false,false,true,false><<<MT * 4, blk, 0, stream>>>(
            NbB, iw + 2 * D_ * D_, ib + 2 * D_, nullptr, VB, BL_, D_, D_);
        rope_k<<<(BL_ * D_ / 8 + 255) / 256, blk, 0, stream>>>(NbB, CT, ST, RopeB);
        // fused q+k projection: W rows [wq;wk], bias [bq;bk], N=1024 -> QKB
        mgemm_k<false,false,true,false><<<MT * 8, blk, 0, stream>>>(
            RopeB, iw, ib, nullptr, QKB, BL_, 1024, D_);
        attn_k<<<B_ * H_ * 8, blk, 0, stream>>>(QKB, VB, mask, RB);
        mgemm_k<false,true,false,false><<<MT * 4, blk, 0, stream>>>(
            RB, owB + (size_t)i * D_ * D_, out_b + i * D_, X, X, BL_, D_, D_);
        ln_k<D_,false,true><<<lnGrid, blk, 0, stream>>>(X, ln2_s + i * D_, ln2_b + i * D_, NbB, BL_);
        mgemm_k<true,false,true,false><<<MT * 16, blk, 0, stream>>>(
            NbB, w1B + (size_t)i * FF_ * D_, b1 + i * FF_, nullptr, FFb16, BL_, FF_, D_);
        mgemm_k<false,true,false,false><<<MT * 4, blk, 0, stream>>>(
            FFb16, w2B + (size_t)i * D_ * FF_, b2 + i * D_, X, X, BL_, D_, FF_);
    }

    pool_k<<<B_, dim3(512), 0, stream>>>(X, mask, GC);
    gpart_k<<<(B_ * 128) / 4, blk, 0, stream>>>(GC, h1_w, h1_b, GP);
    cast_k<<<(int)((S / 8 + 255) / 256), blk, 0, stream>>>(X, NbB, (int)(S / 8));
    mgemm_k<false,false,false,true><<<MT * 1, blk, 0, stream>>>(
        NbB, h1wB, GP, nullptr, Hb, BL_, 128, D_);
    ln_k<128,true,false><<<lnGrid, blk, 0, stream>>>(Hb, hln_s, hln_b, Hb, BL_);
    logits_k<<<lnGrid, blk, 0, stream>>>(Hb, h2_w, h2_b, out, BL_);
}

// Round 8
// 1467.989 us; speedup vs baseline: 1.1614x; 1.0733x over previous
//
#include <hip/hip_runtime.h>
#include <cstdint>
#include <cstddef>

// ---------------- problem constants ----------------
#define B_   16
#define L_   1022
#define E_   1280
#define D_   512
#define H_   8
#define FF_  2048
#define NL_  4
#define DH_  64
#define BL_  (B_*L_)      // 16352
#define EPS_ 1e-5f

typedef unsigned short u16;
typedef unsigned int   u32;
typedef unsigned long long u64;
typedef float f32x4 __attribute__((ext_vector_type(4)));
typedef short s16x8 __attribute__((ext_vector_type(8)));
typedef u32 u32x4 __attribute__((ext_vector_type(4)));

__device__ __forceinline__ u16 f2bf(float f) {
    u32 u = __builtin_bit_cast(u32, f);
    u += 0x7fffu + ((u >> 16) & 1u);
    return (u16)(u >> 16);
}
__device__ __forceinline__ float bf2f(u16 u) {
    return __builtin_bit_cast(float, (u32)u << 16);
}
__device__ __forceinline__ u32 pack2bf(float a, float b) {
    return (u32)f2bf(a) | ((u32)f2bf(b) << 16);
}

// ======================================================================
// fp32 -> bf16 cast, 8 elems/thread
// ======================================================================
__global__ __launch_bounds__(256)
void cast_k(const float* __restrict__ src, u16* __restrict__ dst, int n8) {
    int t = blockIdx.x * 256 + threadIdx.x;
    if (t >= n8) return;
    const float* s = src + (size_t)t * 8;
    float4 a = *(const float4*)(s);
    float4 b = *(const float4*)(s + 4);
    s16x8 o;
    o[0] = (short)f2bf(a.x); o[1] = (short)f2bf(a.y);
    o[2] = (short)f2bf(a.z); o[3] = (short)f2bf(a.w);
    o[4] = (short)f2bf(b.x); o[5] = (short)f2bf(b.y);
    o[6] = (short)f2bf(b.z); o[7] = (short)f2bf(b.w);
    *(s16x8*)(dst + (size_t)t * 8) = o;
}

// h1_w left half [128, 0:512] (row stride 1024) -> packed bf16 [128,512]
__global__ __launch_bounds__(256)
void h1cast_k(const float* __restrict__ src, u16* __restrict__ dst) {
    int t = blockIdx.x * 256 + threadIdx.x;
    if (t >= 128 * 512 / 8) return;
    int row = t >> 6, c8 = (t & 63) << 3;
    const float* s = src + (size_t)row * 1024 + c8;
    float4 a = *(const float4*)(s);
    float4 b = *(const float4*)(s + 4);
    s16x8 o;
    o[0] = (short)f2bf(a.x); o[1] = (short)f2bf(a.y);
    o[2] = (short)f2bf(a.z); o[3] = (short)f2bf(a.w);
    o[4] = (short)f2bf(b.x); o[5] = (short)f2bf(b.y);
    o[6] = (short)f2bf(b.z); o[7] = (short)f2bf(b.w);
    *(s16x8*)(dst + (size_t)row * 512 + c8) = o;
}

// ======================================================================
// RoPE cos/sin tables
// ======================================================================
__global__ void tables_k(float* __restrict__ ct, float* __restrict__ st) {
    int idx = blockIdx.x * blockDim.x + threadIdx.x;
    if (idx >= L_ * DH_) return;
    int l = idx / DH_;
    int d = idx % DH_;
    int j = d & 31;
    float invf = powf(10000.0f, -(float)(2 * j) / (float)DH_);
    float ang = (float)l * invf;
    ct[idx] = cosf(ang);
    st[idx] = sinf(ang);
}

// ======================================================================
// bf16 MFMA GEMM (reg-staged, r5-proven): C = act(A @ W^T + bias)(+resid)
// 128x128 tile, BK=64, 256 threads (4 waves 2x2), 4x4 16x16 frags/wave.
// ======================================================================
template<bool RELU, bool RESID, bool OUTBF, bool ROWBIAS>
__global__ __launch_bounds__(256)
void mgemm_k(const u16* __restrict__ A, const u16* __restrict__ W,
             const float* __restrict__ bias, const float* __restrict__ resid,
             void* __restrict__ Cout, int M, int N, int K)
{
    constexpr int LDT = 72;               // padded LDS row stride (bf16)
    __shared__ u16 As[128 * LDT];
    __shared__ u16 Ws[128 * LDT];
    const int nt = N >> 7;
    const int bx = blockIdx.x % nt;
    const int by = blockIdx.x / nt;
    const int m0 = by << 7, n0 = bx << 7;
    const int tid = threadIdx.x;
    const int lane = tid & 63, wid = tid >> 6;
    const int wr = wid >> 1, wc = wid & 1;
    const int lr = lane & 15, lk = lane >> 4;

    f32x4 acc[4][4];
#pragma unroll
    for (int m = 0; m < 4; m++)
#pragma unroll
        for (int n = 0; n < 4; n++) acc[m][n] = (f32x4)0.0f;

    for (int k0 = 0; k0 < K; k0 += 64) {
        s16x8 va[4], vw[4];
#pragma unroll
        for (int u = 0; u < 4; u++) {
            int ch = tid + (u << 8);          // 16B chunk id, 0..1023
            int r = ch >> 3, c8 = (ch & 7) << 3;
            int ar = m0 + r; if (ar >= M) ar = M - 1;
            va[u] = *(const s16x8*)(A + (size_t)ar * K + k0 + c8);
            vw[u] = *(const s16x8*)(W + (size_t)(n0 + r) * K + k0 + c8);
        }
        __syncthreads();   // previous iteration's LDS reads complete
#pragma unroll
        for (int u = 0; u < 4; u++) {
            int ch = tid + (u << 8);
            int r = ch >> 3, c8 = (ch & 7) << 3;
            *(s16x8*)&As[r * LDT + c8] = va[u];
            *(s16x8*)&Ws[r * LDT + c8] = vw[u];
        }
        __syncthreads();   // tiles staged
#pragma unroll
        for (int kk = 0; kk < 2; kk++) {
            s16x8 af[4], bf[4];
#pragma unroll
            for (int m = 0; m < 4; m++)
                af[m] = *(const s16x8*)&As[(wr * 64 + m * 16 + lr) * LDT + kk * 32 + lk * 8];
#pragma unroll
            for (int n = 0; n < 4; n++)
                bf[n] = *(const s16x8*)&Ws[(wc * 64 + n * 16 + lr) * LDT + kk * 32 + lk * 8];
#pragma unroll
            for (int m = 0; m < 4; m++)
#pragma unroll
                for (int n = 0; n < 4; n++)
                    acc[m][n] = __builtin_amdgcn_mfma_f32_16x16x32_bf16(
                        af[m], bf[n], acc[m][n], 0, 0, 0);
        }
    }

    float bv[4];
    if constexpr (!ROWBIAS) {
#pragma unroll
        for (int n = 0; n < 4; n++) bv[n] = bias[n0 + wc * 64 + n * 16 + lr];
    }
#pragma unroll
    for (int m = 0; m < 4; m++) {
#pragma unroll
        for (int j = 0; j < 4; j++) {
            int row = m0 + wr * 64 + m * 16 + lk * 4 + j;
            if (row >= M) continue;
            const float* rb = nullptr;
            if constexpr (ROWBIAS) rb = bias + (size_t)(row / L_) * N;
#pragma unroll
            for (int n = 0; n < 4; n++) {
                int col = n0 + wc * 64 + n * 16 + lr;
                float c = acc[m][n][j];
                if constexpr (ROWBIAS) c += rb[col];
                else                   c += bv[n];
                if constexpr (RELU) c = fmaxf(c, 0.0f);
                if constexpr (RESID) c += resid[(size_t)row * N + col];
                if constexpr (OUTBF) ((u16*)Cout)[(size_t)row * N + col] = f2bf(c);
                else                 ((float*)Cout)[(size_t)row * N + col] = c;
            }
        }
    }
}

// ======================================================================
// LayerNorm: one wave per row; optional ReLU; optional bf16 output.
// ======================================================================
template<int DD, bool RELU, bool OUTBF>
__global__ __launch_bounds__(256)
void ln_k(const float* __restrict__ x, const float* __restrict__ s,
          const float* __restrict__ bb, void* __restrict__ out, int M)
{
    const int lane = threadIdx.x & 63;
    const int row = (blockIdx.x << 2) + (threadIdx.x >> 6);
    if (row >= M) return;
    const float* xr = x + (size_t)row * DD;
    constexpr int NV = DD / 64;
    float v[NV];
    if constexpr (NV == 8) {
        *(float4*)(v)     = *(const float4*)(xr + lane * 8);
        *(float4*)(v + 4) = *(const float4*)(xr + lane * 8 + 4);
    } else {
        float2 t = *(const float2*)(xr + lane * 2);
        v[0] = t.x; v[1] = t.y;
    }
    float sum = 0.f, sq = 0.f;
#pragma unroll
    for (int e = 0; e < NV; e++) { sum += v[e]; sq += v[e] * v[e]; }
#pragma unroll
    for (int msk = 1; msk < 64; msk <<= 1) {
        sum += __shfl_xor(sum, msk);
        sq  += __shfl_xor(sq, msk);
    }
    const float mean = sum * (1.0f / DD);
    const float var  = sq * (1.0f / DD) - mean * mean;
    const float rstd = rsqrtf(var + EPS_);
#pragma unroll
    for (int e = 0; e < NV; e++) {
        int d = lane * NV + e;
        float r = (v[e] - mean) * rstd * s[d] + bb[d];
        if constexpr (RELU) r = fmaxf(r, 0.0f);
        v[e] = r;
    }
    if constexpr (OUTBF) {
        u16* orow = (u16*)out + (size_t)row * DD;
        if constexpr (NV == 8) {
            s16x8 o;
#pragma unroll
            for (int e = 0; e < 8; e++) o[e] = (short)f2bf(v[e]);
            *(s16x8*)(orow + lane * 8) = o;
        } else {
            orow[lane * 2] = f2bf(v[0]); orow[lane * 2 + 1] = f2bf(v[1]);
        }
    } else {
        float* orow = (float*)out + (size_t)row * DD;
        if constexpr (NV == 8) {
            *(float4*)(orow + lane * 8)     = *(float4*)(v);
            *(float4*)(orow + lane * 8 + 4) = *(float4*)(v + 4);
        } else {
            float2 t; t.x = v[0]; t.y = v[1];
            *(float2*)(orow + lane * 2) = t;
        }
    }
}

// ======================================================================
// RoPE on bf16 [BL,512] -> bf16, 8 elems/thread
// ======================================================================
__global__ __launch_bounds__(256)
void rope_k(const u16* __restrict__ n, const float* __restrict__ ct,
            const float* __restrict__ st, u16* __restrict__ r)
{
    int t = blockIdx.x * 256 + threadIdx.x;
    if (t >= BL_ * D_ / 8) return;
    int idx = t << 3;
    int l = (idx / D_) % L_;
    int d = idx & (D_ - 1);
    int dd = d & 63;
    s16x8 xv = *(const s16x8*)(n + idx);
    int pidx; float sgn;
    if (dd < 32) { pidx = idx + 32; sgn = -1.0f; }
    else         { pidx = idx - 32; sgn =  1.0f; }
    s16x8 pv = *(const s16x8*)(n + pidx);
    float4 c0 = *(const float4*)(ct + l * DH_ + dd);
    float4 c1 = *(const float4*)(ct + l * DH_ + dd + 4);
    float4 s0 = *(const float4*)(st + l * DH_ + dd);
    float4 s1 = *(const float4*)(st + l * DH_ + dd + 4);
    float cc[8] = {c0.x,c0.y,c0.z,c0.w,c1.x,c1.y,c1.z,c1.w};
    float ss[8] = {s0.x,s0.y,s0.z,s0.w,s1.x,s1.y,s1.z,s1.w};
    s16x8 o;
#pragma unroll
    for (int e = 0; e < 8; e++) {
        float xf = bf2f((u16)xv[e]);
        float pf = bf2f((u16)pv[e]);
        o[e] = (short)f2bf(xf * cc[e] + sgn * pf * ss[e]);
    }
    *(s16x8*)(r + idx) = o;
}

// ======================================================================
// MFMA flash attention, swapped-operand (S^T = K Q^T), in-register softmax.
// q,k packed qk[BL,1024] (q col 0, k col 512); v[BL,512].
// block = (b, h, 64-q-tile); 4 waves; wave w owns q = qt*64+w*16+lr (its
// lane's lr IS the q-column). Per 64-key tile:
//   S^T tile n: sacc[n] = mfma(A=Kt rows 16n+lr, B=Q cols q). C: col=q=lr,
//   row=key_local=16n+4*lg+j -> lane holds 16 S values of ONE q-row.
//   Softmax: 15 in-reg fmax/add + 2 shfl_xor(16,32) across the 4 lg-lanes
//   sharing this q. P stays in registers: pack bf16 pairs, redistribute via
//   16 ds_bpermute (src0=lr+32*(lg&1), src1=src0+16, n_s=2kk+(lg>>1)) to
//   form PV B-frags. PV: oacc[n2] = mfma(A=Vt rows d=16n2+lr, B=P^T).
//   O^T: lane holds col q=lr, rows d=16n2+4lg+j. Epilogue transposes via
//   reused Kt LDS for coalesced stores.
// ======================================================================
__global__ __launch_bounds__(256)
void attn_k(const u16* __restrict__ qk, const u16* __restrict__ v,
            const float* __restrict__ mask, u16* __restrict__ o)
{
    constexpr int LDA = 68;
    __shared__ u16 Kt[64 * LDA];
    __shared__ u16 Vt[64 * LDA];
    const int bh = blockIdx.x >> 4, qt = blockIdx.x & 15;
    const int b = bh >> 3, h = bh & 7;
    const int tid = threadIdx.x;
    const int lane = tid & 63, w = tid >> 6;
    const int lr = lane & 15, lg = lane >> 4;
    const size_t basebl = (size_t)b * L_;

    // Q B-frags: lane's q-row = qt*64 + w*16 + lr; k = kk*32 + lg*8 + e
    const int qrow = qt * 64 + w * 16 + lr;
    const int qc = qrow < L_ ? qrow : L_ - 1;
    s16x8 bq[2];
#pragma unroll
    for (int kk = 0; kk < 2; kk++)
        bq[kk] = *(const s16x8*)(qk + (basebl + qc) * 1024 + h * DH_ + kk * 32 + lg * 8);

    f32x4 oacc[4];            // O^T: col q=lr, rows d = 16*n2 + 4*lg + j
#pragma unroll
    for (int n = 0; n < 4; n++) oacc[n] = (f32x4)0.0f;
    float m_run = -1e30f, l_run = 0.f;   // per lane = per q (replicated x4 lg)

    const int st_key = tid >> 3;          // 0..31 (+32 for u=1)
    const int st_d8 = (tid & 7) << 3;
    const int src0 = lr + ((lane & 16) << 1);   // lr + 32*(lg&1)
    const int src1 = src0 + 16;
    const bool ahi = (lg >> 1) != 0;

    for (int kt = 0; kt < 16; kt++) {
        __syncthreads();          // all waves done reading prev Kt/Vt
#pragma unroll
        for (int u = 0; u < 2; u++) {
            int key = st_key + u * 32;
            int gk = kt * 64 + key; if (gk >= L_) gk = L_ - 1;
            s16x8 kv = *(const s16x8*)(qk + (basebl + gk) * 1024 + 512 + h * DH_ + st_d8);
            s16x8 vv = *(const s16x8*)(v  + (basebl + gk) * D_ + h * DH_ + st_d8);
            *(s16x8*)&Kt[key * LDA + st_d8] = kv;
#pragma unroll
            for (int e = 0; e < 8; e++) Vt[(st_d8 + e) * LDA + key] = (u16)vv[e];
        }
        __syncthreads();

        // key validity for all 64 keys of this tile via one ballot
        int gkey = kt * 64 + lane;
        bool vb = (gkey < L_) && (mask[basebl + gkey] > 0.0f);
        u64 vm = __ballot(vb);

        // S^T = K Q^T
        f32x4 sacc[4];
#pragma unroll
        for (int n = 0; n < 4; n++) {
            sacc[n] = (f32x4)0.0f;
#pragma unroll
            for (int kk = 0; kk < 2; kk++) {
                s16x8 ak = *(const s16x8*)&Kt[(n * 16 + lr) * LDA + kk * 32 + lg * 8];
                sacc[n] = __builtin_amdgcn_mfma_f32_16x16x32_bf16(ak, bq[kk], sacc[n], 0, 0, 0);
            }
        }

        // in-register masked scale + row max (lane's 16 values, 1 q-row)
        float p[4][4];
        float tm = -1e30f;
#pragma unroll
        for (int n = 0; n < 4; n++)
#pragma unroll
            for (int j = 0; j < 4; j++) {
                int kl = 16 * n + 4 * lg + j;
                float s = ((vm >> kl) & 1ull) ? sacc[n][j] * 0.125f : -1e30f;
                p[n][j] = s;
                tm = fmaxf(tm, s);
            }
        tm = fmaxf(tm, __shfl_xor(tm, 16));
        tm = fmaxf(tm, __shfl_xor(tm, 32));
        float nm = fmaxf(m_run, tm);
        float corr = __expf(m_run - nm);
        m_run = nm;
        float ts = 0.f;
#pragma unroll
        for (int n = 0; n < 4; n++)
#pragma unroll
            for (int j = 0; j < 4; j++) {
                p[n][j] = __expf(p[n][j] - nm);
                ts += p[n][j];
            }
        ts += __shfl_xor(ts, 16);
        ts += __shfl_xor(ts, 32);
        l_run = l_run * corr + ts;
#pragma unroll
        for (int n = 0; n < 4; n++) oacc[n] *= corr;

        // pack P -> bf16 pairs; redistribute to PV B-frag layout
        u32 pk[4][2];
#pragma unroll
        for (int n = 0; n < 4; n++) {
            pk[n][0] = pack2bf(p[n][0], p[n][1]);
            pk[n][1] = pack2bf(p[n][2], p[n][3]);
        }
        u32 r0[4][2], r1[4][2];
#pragma unroll
        for (int n = 0; n < 4; n++)
#pragma unroll
            for (int i = 0; i < 2; i++) {
                r0[n][i] = (u32)__shfl((int)pk[n][i], src0);
                r1[n][i] = (u32)__shfl((int)pk[n][i], src1);
            }
#pragma unroll
        for (int kk = 0; kk < 2; kk++) {
            u32x4 bw;
            bw[0] = ahi ? r0[2 * kk + 1][0] : r0[2 * kk][0];
            bw[1] = ahi ? r0[2 * kk + 1][1] : r0[2 * kk][1];
            bw[2] = ahi ? r1[2 * kk + 1][0] : r1[2 * kk][0];
            bw[3] = ahi ? r1[2 * kk + 1][1] : r1[2 * kk][1];
            s16x8 bp = __builtin_bit_cast(s16x8, bw);
#pragma unroll
            for (int n2 = 0; n2 < 4; n2++) {
                s16x8 av = *(const s16x8*)&Vt[(n2 * 16 + lr) * LDA + kk * 32 + lg * 8];
                oacc[n2] = __builtin_amdgcn_mfma_f32_16x16x32_bf16(av, bp, oacc[n2], 0, 0, 0);
            }
        }
    }

    // epilogue: normalize, transpose via reused Kt (wave-private 16 rows)
    __syncthreads();   // all waves done with Kt/Vt MFMA reads
    u16* Ol = &Kt[w * 16 * LDA];
    float inv = 1.0f / l_run;
#pragma unroll
    for (int n = 0; n < 4; n++)
#pragma unroll
        for (int j = 0; j < 4; j++)
            Ol[lr * LDA + 16 * n + 4 * lg + j] = f2bf(oacc[n][j] * inv);
    // intra-wave LDS dep: compiler inserts lgkmcnt; then coalesced stores
    int orow = lane >> 2, oc = (lane & 3) * 16;
    int qg = qt * 64 + w * 16 + orow;
    if (qg < L_) {
        s16x8 o0 = *(const s16x8*)&Ol[orow * LDA + oc];
        s16x8 o1 = *(const s16x8*)&Ol[orow * LDA + oc + 8];
        *(s16x8*)(o + (basebl + qg) * D_ + h * DH_ + oc) = o0;
        *(s16x8*)(o + (basebl + qg) * D_ + h * DH_ + oc + 8) = o1;
    }
}

// ======================================================================
// masked mean pool, two-stage. pool1: grid (B,16), partial sums of 64 rows.
// ======================================================================
__global__ __launch_bounds__(512)
void pool1_k(const float* __restrict__ x, const float* __restrict__ mask,
             float* __restrict__ pp, float* __restrict__ mp)
{
    const int b = blockIdx.x, sp = blockIdx.y;
    const int d = threadIdx.x;
    const int l0 = sp * 64;
    float acc = 0.f;
    for (int l = l0; l < l0 + 64 && l < L_; l++)
        acc += x[((size_t)b * L_ + l) * D_ + d] * mask[b * L_ + l];
    pp[((size_t)b * 16 + sp) * D_ + d] = acc;
    if (d == 0) {
        float ms = 0.f;
        for (int l = l0; l < l0 + 64 && l < L_; l++) ms += mask[b * L_ + l];
        mp[b * 16 + sp] = ms;
    }
}

__global__ __launch_bounds__(512)
void pool2_k(const float* __restrict__ pp, const float* __restrict__ mp,
             float* __restrict__ g)
{
    const int b = blockIdx.x;
    const int d = threadIdx.x;
    float acc = 0.f, ms = 0.f;
#pragma unroll
    for (int sp = 0; sp < 16; sp++) {
        acc += pp[((size_t)b * 16 + sp) * D_ + d];
        ms += mp[b * 16 + sp];
    }
    g[b * D_ + d] = acc / ms;
}

// ======================================================================
// gpart[b][j] = h1_b[j] + dot(gctx[b], h1_w[j, 512:1024])  (fp32)
// ======================================================================
__global__ __launch_bounds__(256)
void gpart_k(const float* __restrict__ g, const float* __restrict__ h1w,
             const float* __restrict__ h1b, float* __restrict__ gp)
{
    const int lane = threadIdx.x & 63;
    const int gid = (blockIdx.x << 2) + (threadIdx.x >> 6);
    const int b = gid >> 7, j = gid & 127;
    const float* wr = h1w + (size_t)j * (2 * D_) + D_;
    const float* gr = g + b * D_;
    float4 a0 = *(const float4*)(gr + lane * 8);
    float4 a1 = *(const float4*)(gr + lane * 8 + 4);
    float4 w0 = *(const float4*)(wr + lane * 8);
    float4 w1v = *(const float4*)(wr + lane * 8 + 4);
    float acc = a0.x * w0.x + a0.y * w0.y + a0.z * w0.z + a0.w * w0.w
              + a1.x * w1v.x + a1.y * w1v.y + a1.z * w1v.z + a1.w * w1v.w;
#pragma unroll
    for (int msk = 1; msk < 64; msk <<= 1) acc += __shfl_xor(acc, msk);
    if (lane == 0) gp[b * 128 + j] = acc + h1b[j];
}

// ======================================================================
// logits[m] = h2_b + dot(h[m,0:128], h2_w)
// ======================================================================
__global__ __launch_bounds__(256)
void logits_k(const float* __restrict__ h, const float* __restrict__ w,
              const float* __restrict__ bsc, float* __restrict__ out, int M)
{
    const int lane = threadIdx.x & 63;
    const int row = (blockIdx.x << 2) + (threadIdx.x >> 6);
    if (row >= M) return;
    float2 hv = *(const float2*)(h + (size_t)row * 128 + lane * 2);
    float2 wv = *(const float2*)(w + lane * 2);
    float acc = hv.x * wv.x + hv.y * wv.y;
#pragma unroll
    for (int msk = 1; msk < 64; msk <<= 1) acc += __shfl_xor(acc, msk);
    if (lane == 0) out[row] = acc + bsc[0];
}

// ======================================================================
// host orchestration
// ======================================================================
extern "C" void kernel_launch(void* const* d_in, const int* in_sizes, int n_in,
                              void* d_out, int out_size, void* d_ws, size_t ws_size,
                              hipStream_t stream)
{
    const float* emb       = (const float*)d_in[0];
    const float* mask      = (const float*)d_in[1];
    const float* proj_w    = (const float*)d_in[3];
    const float* proj_b    = (const float*)d_in[4];
    const float* proj_ln_s = (const float*)d_in[5];
    const float* proj_ln_b = (const float*)d_in[6];
    const float* ln1_s     = (const float*)d_in[7];
    const float* ln1_b     = (const float*)d_in[8];
    const float* in_w      = (const float*)d_in[9];
    const float* in_b      = (const float*)d_in[10];
    const float* out_w     = (const float*)d_in[11];
    const float* out_b     = (const float*)d_in[12];
    const float* ln2_s     = (const float*)d_in[13];
    const float* ln2_b     = (const float*)d_in[14];
    const float* w1        = (const float*)d_in[15];
    const float* b1        = (const float*)d_in[16];
    const float* w2        = (const float*)d_in[17];
    const float* b2        = (const float*)d_in[18];
    const float* h1_w      = (const float*)d_in[19];
    const float* h1_b      = (const float*)d_in[20];
    const float* hln_s     = (const float*)d_in[21];
    const float* hln_b     = (const float*)d_in[22];
    const float* h2_w      = (const float*)d_in[23];
    const float* h2_b      = (const float*)d_in[24];
    float* out = (float*)d_out;

    // Workspace map (S = BL*D floats):
    //   [0,S)      X fp32 residual
    //   [S,2S)     Rf fp32 (proj-out, head Hb) / QKB bf16 [BL,1024] (disjoint)
    //   [2S,2.5S)  VB bf16
    //   [2.5S,3S)  NbB bf16
    //   [3S,5S)    FFb16 bf16 [BL,2048]; aliases embB, RopeB, RB (disjoint)
    //   [5S,...)   bf16 weights, CT/ST/GC/GP/Pp/Mp
    float* ws = (float*)d_ws;
    const size_t S = (size_t)BL_ * D_;
    float* X  = ws;
    float* Rf = ws + S;
    u16* QKB   = (u16*)(ws + S);
    u16* VB    = (u16*)(ws + 2 * S);
    u16* NbB   = (u16*)(ws + 2 * S) + S;
    u16* FFb16 = (u16*)(ws + 3 * S);
    u16* RopeB = FFb16;
    u16* embB  = FFb16;
    u16* RB    = (u16*)(ws + 4 * S);
    u16* projwB = (u16*)(ws + 5 * S);
    u16* iwB  = projwB + 512 * 1280;
    u16* owB  = iwB + (size_t)NL_ * 3 * D_ * D_;
    u16* w1B  = owB + (size_t)NL_ * D_ * D_;
    u16* w2B  = w1B + (size_t)NL_ * FF_ * D_;
    u16* h1wB = w2B + (size_t)NL_ * D_ * FF_;
    float* CT = ws + 5 * S + 6651904;
    float* ST = CT + L_ * DH_;
    float* GC = ST + L_ * DH_;
    float* GP = GC + B_ * D_;
    float* Pp = GP + B_ * 128;            // [B*16, 512] partials
    float* Mp = Pp + (size_t)B_ * 16 * D_;
    float* Hb = Rf;

    const int MT = 128;
    const dim3 blk(256);
    const int lnGrid = (BL_ + 3) / 4;

    cast_k<<<(BL_ * E_ / 8 + 255) / 256, blk, 0, stream>>>(emb, embB, BL_ * E_ / 8);
    cast_k<<<(512 * 1280 / 8 + 255) / 256, blk, 0, stream>>>(proj_w, projwB, 512 * 1280 / 8);
    cast_k<<<(NL_ * 3 * D_ * D_ / 8 + 255) / 256, blk, 0, stream>>>(in_w, iwB, NL_ * 3 * D_ * D_ / 8);
    cast_k<<<(NL_ * D_ * D_ / 8 + 255) / 256, blk, 0, stream>>>(out_w, owB, NL_ * D_ * D_ / 8);
    cast_k<<<(NL_ * FF_ * D_ / 8 + 255) / 256, blk, 0, stream>>>(w1, w1B, NL_ * FF_ * D_ / 8);
    cast_k<<<(NL_ * D_ * FF_ / 8 + 255) / 256, blk, 0, stream>>>(w2, w2B, NL_ * D_ * FF_ / 8);
    h1cast_k<<<(128 * 512 / 8 + 255) / 256, blk, 0, stream>>>(h1_w, h1wB);
    tables_k<<<(L_ * DH_ + 255) / 256, blk, 0, stream>>>(CT, ST);

    mgemm_k<false,false,false,false><<<MT * (D_ / 128), blk, 0, stream>>>(
        embB, projwB, proj_b, nullptr, Rf, BL_, D_, E_);
    ln_k<D_,false,false><<<lnGrid, blk, 0, stream>>>(Rf, proj_ln_s, proj_ln_b, X, BL_);

    for (int i = 0; i < NL_; i++) {
        const u16* iw = iwB + (size_t)i * 3 * D_ * D_;
        const float* ib = in_b + (size_t)i * 3 * D_;
        ln_k<D_,false,true><<<lnGrid, blk, 0, stream>>>(X, ln1_s + i * D_, ln1_b + i * D_, NbB, BL_);
        mgemm_k<false,false,true,false><<<MT * 4, blk, 0, stream>>>(
            NbB, iw + 2 * D_ * D_, ib + 2 * D_, nullptr, VB, BL_, D_, D_);
        rope_k<<<(BL_ * D_ / 8 + 255) / 256, blk, 0, stream>>>(NbB, CT, ST, RopeB);
        // fused q+k projection: W rows [wq;wk], bias [bq;bk], N=1024 -> QKB
        mgemm_k<false,false,true,false><<<MT * 8, blk, 0, stream>>>(
            RopeB, iw, ib, nullptr, QKB, BL_, 1024, D_);
        attn_k<<<B_ * H_ * 16, blk, 0, stream>>>(QKB, VB, mask, RB);
        mgemm_k<false,true,false,false><<<MT * 4, blk, 0, stream>>>(
            RB, owB + (size_t)i * D_ * D_, out_b + i * D_, X, X, BL_, D_, D_);
        ln_k<D_,false,true><<<lnGrid, blk, 0, stream>>>(X, ln2_s + i * D_, ln2_b + i * D_, NbB, BL_);
        mgemm_k<true,false,true,false><<<MT * 16, blk, 0, stream>>>(
            NbB, w1B + (size_t)i * FF_ * D_, b1 + i * FF_, nullptr, FFb16, BL_, FF_, D_);
        mgemm_k<false,true,false,false><<<MT * 4, blk, 0, stream>>>(
            FFb16, w2B + (size_t)i * D_ * FF_, b2 + i * D_, X, X, BL_, D_, FF_);
    }

    pool1_k<<<dim3(B_, 16), dim3(512), 0, stream>>>(X, mask, Pp, Mp);
    pool2_k<<<B_, dim3(512), 0, stream>>>(Pp, Mp, GC);
    gpart_k<<<(B_ * 128) / 4, blk, 0, stream>>>(GC, h1_w, h1_b, GP);
    cast_k<<<(int)((S / 8 + 255) / 256), blk, 0, stream>>>(X, NbB, (int)(S / 8));
    mgemm_k<false,false,false,true><<<MT * 1, blk, 0, stream>>>(
        NbB, h1wB, GP, nullptr, Hb, BL_, 128, D_);
    ln_k<128,true,false><<<lnGrid, blk, 0, stream>>>(Hb, hln_s, hln_b, Hb, BL_);
    logits_k<<<lnGrid, blk, 0, stream>>>(Hb, h2_w, h2_b, out, BL_);
}